// Round 1
// baseline (389.961 us; speedup 1.0000x reference)
//
#include <hip/hip_runtime.h>
#include <hip/hip_bf16.h>

typedef __attribute__((ext_vector_type(8))) short short8;
typedef __attribute__((ext_vector_type(4))) float floatx4;
typedef __attribute__((ext_vector_type(4))) unsigned int uintx4;

#define BB 8
#define TT 4096
#define CC 1024
#define HH 128

__device__ __forceinline__ unsigned short f2bf(float f) {
    unsigned int u = __float_as_uint(f);
    u += 0x7fffu + ((u >> 16) & 1u);   // round-to-nearest-even
    return (unsigned short)(u >> 16);
}

// ---------------- x fp32 -> bf16 ----------------
__global__ void conv_x(const float* __restrict__ x, unsigned short* __restrict__ xb) {
    long i = ((long)blockIdx.x * blockDim.x + threadIdx.x) * 8;
    floatx4 a = *(const floatx4*)(x + i);
    floatx4 b = *(const floatx4*)(x + i + 4);
    uintx4 o;
    o[0] = (unsigned)f2bf(a[0]) | ((unsigned)f2bf(a[1]) << 16);
    o[1] = (unsigned)f2bf(a[2]) | ((unsigned)f2bf(a[3]) << 16);
    o[2] = (unsigned)f2bf(b[0]) | ((unsigned)f2bf(b[1]) << 16);
    o[3] = (unsigned)f2bf(b[2]) | ((unsigned)f2bf(b[3]) << 16);
    *(uintx4*)(xb + i) = o;
}

// ---------------- W [C][H] fp32 -> Wt [3][H][C] bf16 (transposed) ----------------
__global__ void conv_w(const float* __restrict__ Wq, const float* __restrict__ Wk,
                       const float* __restrict__ Wv, unsigned short* __restrict__ Wt) {
    int t = blockIdx.x * 256 + threadIdx.x;   // 0 .. 3*128*1024-1
    int w = t >> 17;
    int rem = t & 131071;
    int n = rem >> 10;
    int k = rem & 1023;
    const float* W = (w == 0) ? Wq : ((w == 1) ? Wk : Wv);
    Wt[t] = f2bf(W[k * HH + n]);
}

// ---------------- fused QKV projection GEMM ----------------
// grid (M/128, 3); block 256. out: Qb (scaled, bf16 [B*T][H]), Kb, Vt ([B][H][T])
__global__ __launch_bounds__(256) void proj_gemm(
    const unsigned short* __restrict__ xb, const unsigned short* __restrict__ Wt,
    const float* __restrict__ bq, const float* __restrict__ bk, const float* __restrict__ bv,
    unsigned short* __restrict__ Qb, unsigned short* __restrict__ Kb,
    unsigned short* __restrict__ Vt) {
    __shared__ unsigned short As[128 * 72];
    __shared__ unsigned short Bs[128 * 72];
    const int w = blockIdx.y;
    const int mbase = blockIdx.x * 128;
    const int tid = threadIdx.x;
    const int lane = tid & 63, wv = tid >> 6;
    const int quad = lane >> 4, l15 = lane & 15;
    const unsigned short* Wp = Wt + w * (HH * CC);

    floatx4 acc[2][8];
#pragma unroll
    for (int i = 0; i < 2; ++i)
#pragma unroll
        for (int j = 0; j < 8; ++j) {
            floatx4 z = {0.f, 0.f, 0.f, 0.f};
            acc[i][j] = z;
        }

    for (int kt = 0; kt < CC / 64; ++kt) {
#pragma unroll
        for (int h = 0; h < 4; ++h) {
            int c = tid + h * 256;
            int row = c >> 3, cc = c & 7;
            *(uintx4*)&As[row * 72 + cc * 8] =
                *(const uintx4*)(xb + (long)(mbase + row) * CC + kt * 64 + cc * 8);
            *(uintx4*)&Bs[row * 72 + cc * 8] =
                *(const uintx4*)(Wp + (long)row * CC + kt * 64 + cc * 8);
        }
        __syncthreads();
#pragma unroll
        for (int ks = 0; ks < 2; ++ks) {
            short8 af[2];
#pragma unroll
            for (int mi = 0; mi < 2; ++mi)
                af[mi] = *(const short8*)&As[(wv * 32 + mi * 16 + l15) * 72 + ks * 32 + quad * 8];
#pragma unroll
            for (int ni = 0; ni < 8; ++ni) {
                short8 bfr = *(const short8*)&Bs[(ni * 16 + l15) * 72 + ks * 32 + quad * 8];
#pragma unroll
                for (int mi = 0; mi < 2; ++mi)
                    acc[mi][ni] = __builtin_amdgcn_mfma_f32_16x16x32_bf16(af[mi], bfr, acc[mi][ni], 0, 0, 0);
            }
        }
        __syncthreads();
    }

    const float* bias = (w == 0) ? bq : ((w == 1) ? bk : bv);
#pragma unroll
    for (int mi = 0; mi < 2; ++mi)
#pragma unroll
        for (int ni = 0; ni < 8; ++ni) {
            int col = ni * 16 + l15;
            float bval = bias[col];
#pragma unroll
            for (int r = 0; r < 4; ++r) {
                int row = mbase + wv * 32 + mi * 16 + quad * 4 + r;
                float v = acc[mi][ni][r] + bval;
                if (w == 0) {
                    Qb[(long)row * HH + col] = f2bf(v * 0.08838834764831845f);
                } else if (w == 1) {
                    Kb[(long)row * HH + col] = f2bf(v);
                } else {
                    int bb = row >> 12, t = row & 4095;
                    Vt[(long)bb * (HH * TT) + (long)col * TT + t] = f2bf(v);
                }
            }
        }
}

// ---------------- flash attention, causal ----------------
// grid 512 (= B * T/64, reversed qb for load balance); block 256 (4 waves x 16 q-rows)
__global__ __launch_bounds__(256) void attn(
    const unsigned short* __restrict__ Qb, const unsigned short* __restrict__ Kb,
    const unsigned short* __restrict__ Vt, float* __restrict__ out) {
    __shared__ unsigned short Ks[64 * 136];
    __shared__ unsigned short Vs[128 * 72];
    __shared__ unsigned short Ps[4 * 16 * 72];
    const int b = blockIdx.x & 7;
    const int qb = 63 - (blockIdx.x >> 3);
    const int tid = threadIdx.x, lane = tid & 63, wv = tid >> 6;
    const int quad = lane >> 4, l15 = lane & 15;

    short8 qf[4];
    {
        const unsigned short* qp = Qb + ((long)b * TT + qb * 64 + wv * 16 + l15) * HH + quad * 8;
#pragma unroll
        for (int ks = 0; ks < 4; ++ks) qf[ks] = *(const short8*)(qp + ks * 32);
    }
    floatx4 o[8];
#pragma unroll
    for (int i = 0; i < 8; ++i) {
        floatx4 z = {0.f, 0.f, 0.f, 0.f};
        o[i] = z;
    }
    float m_r[4] = {-1e30f, -1e30f, -1e30f, -1e30f};
    float l_r[4] = {0.f, 0.f, 0.f, 0.f};

    const unsigned short* Kbb = Kb + (long)b * TT * HH;
    const unsigned short* Vbb = Vt + (long)b * HH * TT;
    unsigned short* Pw = &Ps[wv * 16 * 72];

    for (int kb = 0; kb <= qb; ++kb) {
#pragma unroll
        for (int h = 0; h < 4; ++h) {
            int c = tid + h * 256;
            int kr = c >> 4, kc = c & 15;
            *(uintx4*)&Ks[kr * 136 + kc * 8] =
                *(const uintx4*)(Kbb + (long)(kb * 64 + kr) * HH + kc * 8);
            int vr = c >> 3, vc = c & 7;
            *(uintx4*)&Vs[vr * 72 + vc * 8] =
                *(const uintx4*)(Vbb + (long)vr * TT + kb * 64 + vc * 8);
        }
        __syncthreads();

        floatx4 s[4];
#pragma unroll
        for (int nt = 0; nt < 4; ++nt) {
            floatx4 z = {0.f, 0.f, 0.f, 0.f};
            s[nt] = z;
        }
#pragma unroll
        for (int ks = 0; ks < 4; ++ks)
#pragma unroll
            for (int nt = 0; nt < 4; ++nt) {
                short8 kf = *(const short8*)&Ks[(nt * 16 + l15) * 136 + ks * 32 + quad * 8];
                s[nt] = __builtin_amdgcn_mfma_f32_16x16x32_bf16(qf[ks], kf, s[nt], 0, 0, 0);
            }

        if (kb == qb) {  // diagonal block: causal mask (global offsets equal)
            int rowl = wv * 16 + quad * 4;
#pragma unroll
            for (int nt = 0; nt < 4; ++nt) {
                int col = nt * 16 + l15;
#pragma unroll
                for (int r = 0; r < 4; ++r)
                    if (col > rowl + r) s[nt][r] = -1e30f;
            }
        }

        float alpha[4];
#pragma unroll
        for (int r = 0; r < 4; ++r) {
            float mx = fmaxf(fmaxf(s[0][r], s[1][r]), fmaxf(s[2][r], s[3][r]));
#pragma unroll
            for (int off = 1; off < 16; off <<= 1) mx = fmaxf(mx, __shfl_xor(mx, off));
            float mnew = fmaxf(m_r[r], mx);
            alpha[r] = __expf(m_r[r] - mnew);
            m_r[r] = mnew;
            float rs = 0.f;
#pragma unroll
            for (int nt = 0; nt < 4; ++nt) {
                float p = __expf(s[nt][r] - mnew);
                s[nt][r] = p;
                rs += p;
            }
#pragma unroll
            for (int off = 1; off < 16; off <<= 1) rs += __shfl_xor(rs, off);
            l_r[r] = l_r[r] * alpha[r] + rs;
        }
#pragma unroll
        for (int hn = 0; hn < 8; ++hn)
#pragma unroll
            for (int r = 0; r < 4; ++r) o[hn][r] *= alpha[r];

        // P: C-layout -> A-operand layout via per-wave LDS (same-wave DS ops are in-order)
#pragma unroll
        for (int nt = 0; nt < 4; ++nt)
#pragma unroll
            for (int r = 0; r < 4; ++r)
                Pw[(quad * 4 + r) * 72 + nt * 16 + l15] = f2bf(s[nt][r]);

#pragma unroll
        for (int k2 = 0; k2 < 2; ++k2) {
            short8 pf = *(const short8*)&Pw[l15 * 72 + k2 * 32 + quad * 8];
#pragma unroll
            for (int hn = 0; hn < 8; ++hn) {
                short8 vf = *(const short8*)&Vs[(hn * 16 + l15) * 72 + k2 * 32 + quad * 8];
                o[hn] = __builtin_amdgcn_mfma_f32_16x16x32_bf16(pf, vf, o[hn], 0, 0, 0);
            }
        }
        __syncthreads();
    }

    long obase = ((long)b * TT + qb * 64 + wv * 16) * HH;
#pragma unroll
    for (int hn = 0; hn < 8; ++hn)
#pragma unroll
        for (int r = 0; r < 4; ++r)
            out[obase + (quad * 4 + r) * HH + hn * 16 + l15] = o[hn][r] / l_r[r];
}

extern "C" void kernel_launch(void* const* d_in, const int* in_sizes, int n_in,
                              void* d_out, int out_size, void* d_ws, size_t ws_size,
                              hipStream_t stream) {
    const float* x  = (const float*)d_in[0];
    const float* Wq = (const float*)d_in[1];
    const float* bq = (const float*)d_in[2];
    const float* Wk = (const float*)d_in[3];
    const float* bk = (const float*)d_in[4];
    const float* Wv = (const float*)d_in[5];
    const float* bv = (const float*)d_in[6];
    float* out = (float*)d_out;

    char* ws = (char*)d_ws;
    unsigned short* xb = (unsigned short*)(ws);               // 8*4096*1024 bf16 = 64 MiB
    unsigned short* Wt = (unsigned short*)(ws + 67108864);    // 3*128*1024 bf16
    unsigned short* Qb = (unsigned short*)(ws + 67895296);    // 8*4096*128 bf16 (pre-scaled)
    unsigned short* Kb = (unsigned short*)(ws + 76283904);    // 8*4096*128 bf16
    unsigned short* Vt = (unsigned short*)(ws + 84672512);    // 8*128*4096 bf16 (transposed)
    // total ws use: 93,061,120 bytes

    conv_x<<<16384, 256, 0, stream>>>(x, xb);
    conv_w<<<1536, 256, 0, stream>>>(Wq, Wk, Wv, Wt);
    proj_gemm<<<dim3(256, 3), 256, 0, stream>>>(xb, Wt, bq, bk, bv, Qb, Kb, Vt);
    attn<<<512, 256, 0, stream>>>(Qb, Kb, Vt, out);
}

// Round 3
// 337.621 us; speedup vs baseline: 1.1550x; 1.1550x over previous
//
#include <hip/hip_runtime.h>
#include <hip/hip_bf16.h>

typedef __attribute__((ext_vector_type(8))) short short8;
typedef __attribute__((ext_vector_type(4))) float floatx4;
typedef __attribute__((ext_vector_type(4))) unsigned int uintx4;

#define BB 8
#define TT 4096
#define CC 1024
#define HH 128
#define BT (BB * TT)

__device__ __forceinline__ unsigned short f2bf(float f) {
    unsigned int u = __float_as_uint(f);
    u += 0x7fffu + ((u >> 16) & 1u);   // round-to-nearest-even
    return (unsigned short)(u >> 16);
}

// ---------------- W [C][H] fp32 (x3) -> Wt [3*H][C] bf16 transposed, coalesced ----------------
__global__ void conv_w(const float* __restrict__ Wq, const float* __restrict__ Wk,
                       const float* __restrict__ Wv, unsigned short* __restrict__ Wt) {
    __shared__ float tile[32][33];
    const int w = blockIdx.z, nt = blockIdx.y, kt = blockIdx.x;
    const int tx = threadIdx.x, ty = threadIdx.y;  // 32 x 8
    const float* W = (w == 0) ? Wq : ((w == 1) ? Wk : Wv);
#pragma unroll
    for (int i = 0; i < 4; ++i)
        tile[ty + 8 * i][tx] = W[(kt * 32 + ty + 8 * i) * HH + nt * 32 + tx];
    __syncthreads();
#pragma unroll
    for (int i = 0; i < 4; ++i)
        Wt[w * (HH * CC) + (nt * 32 + ty + 8 * i) * CC + kt * 32 + tx] = f2bf(tile[tx][ty + 8 * i]);
}

// ---------------- fused single-pass QKV projection ----------------
// grid 512 (M/64); block 256 = 4 waves x 16 rows; N = 384 (Q|K|V)
__global__ __launch_bounds__(256) void proj_gemm(
    const float* __restrict__ x, const unsigned short* __restrict__ Wt,
    const float* __restrict__ bq, const float* __restrict__ bk, const float* __restrict__ bv,
    unsigned short* __restrict__ Qb, unsigned short* __restrict__ Kb,
    unsigned short* __restrict__ Vt) {
    __shared__ unsigned short As[64 * 72];
    __shared__ unsigned short Bs[384 * 72];
    const int mbase = blockIdx.x * 64;
    const int tid = threadIdx.x, lane = tid & 63, wv = tid >> 6;
    const int quad = lane >> 4, l15 = lane & 15;
    const int arow = tid >> 2, aseg = tid & 3;

    floatx4 acc[24];
#pragma unroll
    for (int i = 0; i < 24; ++i) {
        floatx4 z = {0.f, 0.f, 0.f, 0.f};
        acc[i] = z;
    }

    for (int kt = 0; kt < 16; ++kt) {
        {   // A: 64x64 fp32 -> bf16 into LDS (each thread covers 16 shorts)
            const float* xp = x + (long)(mbase + arow) * CC + kt * 64 + aseg * 16;
            floatx4 f0 = *(const floatx4*)(xp);
            floatx4 f1 = *(const floatx4*)(xp + 4);
            floatx4 f2 = *(const floatx4*)(xp + 8);
            floatx4 f3 = *(const floatx4*)(xp + 12);
            uintx4 p0, p1;
            p0[0] = (unsigned)f2bf(f0[0]) | ((unsigned)f2bf(f0[1]) << 16);
            p0[1] = (unsigned)f2bf(f0[2]) | ((unsigned)f2bf(f0[3]) << 16);
            p0[2] = (unsigned)f2bf(f1[0]) | ((unsigned)f2bf(f1[1]) << 16);
            p0[3] = (unsigned)f2bf(f1[2]) | ((unsigned)f2bf(f1[3]) << 16);
            p1[0] = (unsigned)f2bf(f2[0]) | ((unsigned)f2bf(f2[1]) << 16);
            p1[1] = (unsigned)f2bf(f2[2]) | ((unsigned)f2bf(f2[3]) << 16);
            p1[2] = (unsigned)f2bf(f3[0]) | ((unsigned)f2bf(f3[1]) << 16);
            p1[3] = (unsigned)f2bf(f3[2]) | ((unsigned)f2bf(f3[3]) << 16);
            *(uintx4*)&As[arow * 72 + aseg * 16] = p0;
            *(uintx4*)&As[arow * 72 + aseg * 16 + 8] = p1;
        }
#pragma unroll
        for (int h = 0; h < 12; ++h) {  // B: 384 rows x 64 shorts, 8-short pieces, full coverage
            int c = tid + h * 256;
            int row = c >> 3, seg = c & 7;
            *(uintx4*)&Bs[row * 72 + seg * 8] =
                *(const uintx4*)(Wt + (long)row * CC + kt * 64 + seg * 8);
        }
        __syncthreads();
        short8 af0 = *(const short8*)&As[(wv * 16 + l15) * 72 + quad * 8];
        short8 af1 = *(const short8*)&As[(wv * 16 + l15) * 72 + 32 + quad * 8];
#pragma unroll
        for (int ni = 0; ni < 24; ++ni) {
            short8 b0 = *(const short8*)&Bs[(ni * 16 + l15) * 72 + quad * 8];
            short8 b1 = *(const short8*)&Bs[(ni * 16 + l15) * 72 + 32 + quad * 8];
            acc[ni] = __builtin_amdgcn_mfma_f32_16x16x32_bf16(af0, b0, acc[ni], 0, 0, 0);
            acc[ni] = __builtin_amdgcn_mfma_f32_16x16x32_bf16(af1, b1, acc[ni], 0, 0, 0);
        }
        __syncthreads();
    }

#pragma unroll
    for (int ni = 0; ni < 24; ++ni) {
        int col = ni * 16 + l15;
        int wsel = col >> 7, h = col & 127;
        float bval = (wsel == 0) ? bq[h] : ((wsel == 1) ? bk[h] : bv[h]);
#pragma unroll
        for (int r = 0; r < 4; ++r) {
            int row = mbase + wv * 16 + quad * 4 + r;
            float v = acc[ni][r] + bval;
            if (wsel == 0) {
                Qb[(long)row * HH + h] = f2bf(v * 0.08838834764831845f);
            } else if (wsel == 1) {
                Kb[(long)row * HH + h] = f2bf(v);
            } else {
                int bb = row >> 12, t = row & 4095;
                Vt[(long)bb * (HH * TT) + (long)h * TT + t] = f2bf(v);
            }
        }
    }
}

// ---------------- flash attention, causal, split-KV S=2 ----------------
// grid 1024 = 64 qb (descending) x 8 b x 2 s; block 256 (4 waves x 16 q-rows)
__global__ __launch_bounds__(256) void attn(
    const unsigned short* __restrict__ Qb, const unsigned short* __restrict__ Kb,
    const unsigned short* __restrict__ Vt, unsigned short* __restrict__ Op0,
    unsigned short* __restrict__ Op1, float2* __restrict__ Ml) {
    __shared__ unsigned short Ks[64 * 136];
    __shared__ unsigned short Vs[128 * 72];
    __shared__ unsigned short Ps[4 * 16 * 72];
    const int gid = blockIdx.x;
    const int qb = 63 - (gid >> 4);
    const int sub = gid & 15;
    const int b = sub & 7;
    const int s = sub >> 3;
    const int mid = (qb + 1) >> 1;
    const int lo = (s == 0) ? 0 : mid;
    const int hi = (s == 0) ? mid : qb + 1;
    const int tid = threadIdx.x, lane = tid & 63, wv = tid >> 6;
    const int quad = lane >> 4, l15 = lane & 15;

    short8 qf[4];
    {
        const unsigned short* qp = Qb + ((long)b * TT + qb * 64 + wv * 16 + l15) * HH + quad * 8;
#pragma unroll
        for (int ks = 0; ks < 4; ++ks) qf[ks] = *(const short8*)(qp + ks * 32);
    }
    floatx4 o[8];
#pragma unroll
    for (int i = 0; i < 8; ++i) {
        floatx4 z = {0.f, 0.f, 0.f, 0.f};
        o[i] = z;
    }
    float m_r[4] = {-1e30f, -1e30f, -1e30f, -1e30f};
    float l_r[4] = {0.f, 0.f, 0.f, 0.f};

    const unsigned short* Kbb = Kb + (long)b * TT * HH;
    const unsigned short* Vbb = Vt + (long)b * HH * TT;
    unsigned short* Pw = &Ps[wv * 16 * 72];

    for (int kb = lo; kb < hi; ++kb) {
#pragma unroll
        for (int h = 0; h < 4; ++h) {
            int c = tid + h * 256;
            int kr = c >> 4, kc = c & 15;
            *(uintx4*)&Ks[kr * 136 + kc * 8] =
                *(const uintx4*)(Kbb + (long)(kb * 64 + kr) * HH + kc * 8);
            int vr = c >> 3, vc = c & 7;
            *(uintx4*)&Vs[vr * 72 + vc * 8] =
                *(const uintx4*)(Vbb + (long)vr * TT + kb * 64 + vc * 8);
        }
        __syncthreads();

        floatx4 sArr[4];
#pragma unroll
        for (int nt = 0; nt < 4; ++nt) {
            floatx4 z = {0.f, 0.f, 0.f, 0.f};
            sArr[nt] = z;
        }
#pragma unroll
        for (int ks = 0; ks < 4; ++ks)
#pragma unroll
            for (int nt = 0; nt < 4; ++nt) {
                short8 kf = *(const short8*)&Ks[(nt * 16 + l15) * 136 + ks * 32 + quad * 8];
                sArr[nt] = __builtin_amdgcn_mfma_f32_16x16x32_bf16(qf[ks], kf, sArr[nt], 0, 0, 0);
            }

        if (kb == qb) {  // diagonal block: causal mask
            int rowl = wv * 16 + quad * 4;
#pragma unroll
            for (int nt = 0; nt < 4; ++nt) {
                int col = nt * 16 + l15;
#pragma unroll
                for (int r = 0; r < 4; ++r)
                    if (col > rowl + r) sArr[nt][r] = -1e30f;
            }
        }

        float alpha[4];
#pragma unroll
        for (int r = 0; r < 4; ++r) {
            float mx = fmaxf(fmaxf(sArr[0][r], sArr[1][r]), fmaxf(sArr[2][r], sArr[3][r]));
#pragma unroll
            for (int off = 1; off < 16; off <<= 1) mx = fmaxf(mx, __shfl_xor(mx, off));
            float mnew = fmaxf(m_r[r], mx);
            alpha[r] = __expf(m_r[r] - mnew);
            m_r[r] = mnew;
            float rs = 0.f;
#pragma unroll
            for (int nt = 0; nt < 4; ++nt) {
                float p = __expf(sArr[nt][r] - mnew);
                sArr[nt][r] = p;
                rs += p;
            }
#pragma unroll
            for (int off = 1; off < 16; off <<= 1) rs += __shfl_xor(rs, off);
            l_r[r] = l_r[r] * alpha[r] + rs;
        }
#pragma unroll
        for (int hn = 0; hn < 8; ++hn)
#pragma unroll
            for (int r = 0; r < 4; ++r) o[hn][r] *= alpha[r];

        // P: C-layout -> A-operand layout via per-wave LDS
#pragma unroll
        for (int nt = 0; nt < 4; ++nt)
#pragma unroll
            for (int r = 0; r < 4; ++r)
                Pw[(quad * 4 + r) * 72 + nt * 16 + l15] = f2bf(sArr[nt][r]);

#pragma unroll
        for (int k2 = 0; k2 < 2; ++k2) {
            short8 pf = *(const short8*)&Pw[l15 * 72 + k2 * 32 + quad * 8];
#pragma unroll
            for (int hn = 0; hn < 8; ++hn) {
                short8 vf = *(const short8*)&Vs[(hn * 16 + l15) * 72 + k2 * 32 + quad * 8];
                o[hn] = __builtin_amdgcn_mfma_f32_16x16x32_bf16(pf, vf, o[hn], 0, 0, 0);
            }
        }
        __syncthreads();
    }

    unsigned short* Op = (s == 0) ? Op0 : Op1;
    long rbase = (long)b * TT + qb * 64 + wv * 16 + quad * 4;
    if (hi > lo) {
#pragma unroll
        for (int hn = 0; hn < 8; ++hn)
#pragma unroll
            for (int r = 0; r < 4; ++r)
                Op[(rbase + r) * HH + hn * 16 + l15] = f2bf(o[hn][r] / l_r[r]);
    }
    if (l15 == 0) {
#pragma unroll
        for (int r = 0; r < 4; ++r) {
            float2 ml;
            ml.x = m_r[r];
            ml.y = l_r[r];
            Ml[(long)s * BT + rbase + r] = ml;
        }
    }
}

// ---------------- merge the two KV-chunk partials ----------------
__global__ __launch_bounds__(256) void merge_kern(
    const unsigned short* __restrict__ Op0, const unsigned short* __restrict__ Op1,
    const float2* __restrict__ Ml, float* __restrict__ out) {
    long e = ((long)blockIdx.x * 256 + threadIdx.x) * 8;
    long row = e >> 7;
    float2 a = Ml[row];
    float2 c = Ml[BT + row];
    float ms = fmaxf(a.x, c.x);
    float w0 = a.y * __expf(a.x - ms);
    float w1 = c.y * __expf(c.x - ms);
    float inv = 1.f / (w0 + w1);
    w0 *= inv;
    w1 *= inv;
    uintx4 p0 = *(const uintx4*)(Op0 + e);
    uintx4 p1 = *(const uintx4*)(Op1 + e);
    floatx4 o0, o1;
#pragma unroll
    for (int j = 0; j < 4; ++j) {
        float a0 = __uint_as_float(p0[j] << 16);
        float a1 = __uint_as_float(p0[j] & 0xffff0000u);
        float b0 = __uint_as_float(p1[j] << 16);
        float b1 = __uint_as_float(p1[j] & 0xffff0000u);
        if (j < 2) {
            o0[2 * j] = w0 * a0 + w1 * b0;
            o0[2 * j + 1] = w0 * a1 + w1 * b1;
        } else {
            o1[2 * (j - 2)] = w0 * a0 + w1 * b0;
            o1[2 * (j - 2) + 1] = w0 * a1 + w1 * b1;
        }
    }
    *(floatx4*)(out + e) = o0;
    *(floatx4*)(out + e + 4) = o1;
}

extern "C" void kernel_launch(void* const* d_in, const int* in_sizes, int n_in,
                              void* d_out, int out_size, void* d_ws, size_t ws_size,
                              hipStream_t stream) {
    const float* x  = (const float*)d_in[0];
    const float* Wq = (const float*)d_in[1];
    const float* bq = (const float*)d_in[2];
    const float* Wk = (const float*)d_in[3];
    const float* bk = (const float*)d_in[4];
    const float* Wv = (const float*)d_in[5];
    const float* bv = (const float*)d_in[6];
    float* out = (float*)d_out;

    char* ws = (char*)d_ws;
    unsigned short* Wt  = (unsigned short*)(ws);              // 786,432 B
    unsigned short* Qb  = (unsigned short*)(ws + 1048576);    // 8,388,608 (pre-scaled)
    unsigned short* Kb  = (unsigned short*)(ws + 9437184);    // 8,388,608
    unsigned short* Vt  = (unsigned short*)(ws + 17825792);   // 8,388,608 ([B][H][T])
    unsigned short* Op0 = (unsigned short*)(ws + 26214400);   // 8,388,608 bf16 partial
    unsigned short* Op1 = (unsigned short*)(ws + 34603008);   // 8,388,608 bf16 partial
    float2*         Ml  = (float2*)(ws + 42991616);           // 524,288 (m,l) x 2 chunks
    // total ws use: 43,515,904 bytes

    conv_w<<<dim3(32, 4, 3), dim3(32, 8), 0, stream>>>(Wq, Wk, Wv, Wt);
    proj_gemm<<<512, 256, 0, stream>>>(x, Wt, bq, bk, bv, Qb, Kb, Vt);
    attn<<<1024, 256, 0, stream>>>(Qb, Kb, Vt, Op0, Op1, Ml);
    merge_kern<<<2048, 256, 0, stream>>>(Op0, Op1, Ml, out);
}